// Round 12
// baseline (872.372 us; speedup 1.0000x reference)
//
#include <hip/hip_runtime.h>
#include <hip/hip_bf16.h>
#include <math.h>

#define NN   100000
#define EE   1000000
#define CCH  256      // context channels
#define DMC  128      // stage_metrics channels
#define HDC  192      // hidden of final transform
#define OUTC 128      // out channels
#define ET   64       // edges per k_edge_mlp block (4 m-tiles); EE%ET==0
#define MSB  132      // bf16 msg-tile row stride (elems)
#define GS   391      // scan grid: ceil(NN/256)

typedef unsigned short u16;
using bf16x8 = __attribute__((ext_vector_type(8))) short;
using f32x4  = __attribute__((ext_vector_type(4))) float;
using u16x4  = __attribute__((ext_vector_type(4))) unsigned short;
using u16x8  = __attribute__((ext_vector_type(8))) unsigned short;

__device__ __forceinline__ float selu_f(float x) {
    const float sc = 1.0507009873554804934193349852946f;
    const float c1 = 1.7580993408473765792727863477367f;  // sc*alpha
    const float e = __expf(x);
    return x > 0.0f ? sc * x : __builtin_fmaf(c1, e, -c1);
}
__device__ __forceinline__ u16 f2bf(float f) {
    union { __hip_bfloat16 h; u16 u; } c;
    c.h = __float2bfloat16(f);
    return c.u;
}
__device__ __forceinline__ float bf2f(u16 h) {
    return __uint_as_float(((unsigned int)h) << 16);
}

// ---------------- K1: node transform as bf16 MFMA GEMM -------------------
__global__ __launch_bounds__(256, 2) void k_node_gemm(
    const float* __restrict__ ss, const float* __restrict__ se,
    const float* __restrict__ ctx, const u16* __restrict__ W0p,
    const float* __restrict__ bl, const float* __restrict__ br,
    u16* __restrict__ clb, u16* __restrict__ crb)
{
    __shared__ __align__(16) char Xs[64 * 512];  // [64][256] bf16 swizzled
    const int tid = threadIdx.x;
    const int wave = tid >> 6, lane = tid & 63;
    const int node0 = blockIdx.x * 64;

    {
        const int r = lane;
        const int nd = min(node0 + r, NN - 1);
#pragma unroll
        for (int i = 0; i < 8; ++i) {
            const int c0 = wave * 64 + i * 8;
            float4 va, vb;
            {
                const int c = c0;
                if (c < 16)       va = *reinterpret_cast<const float4*>(ss + nd * 16 + c);
                else if (c < 240) va = *reinterpret_cast<const float4*>(ctx + (size_t)nd * 224 + (c - 16));
                else              va = *reinterpret_cast<const float4*>(se + nd * 16 + (c - 240));
            }
            {
                const int c = c0 + 4;
                if (c < 16)       vb = *reinterpret_cast<const float4*>(ss + nd * 16 + c);
                else if (c < 240) vb = *reinterpret_cast<const float4*>(ctx + (size_t)nd * 224 + (c - 16));
                else              vb = *reinterpret_cast<const float4*>(se + nd * 16 + (c - 240));
            }
            u16x8 v;
            v[0] = f2bf(va.x); v[1] = f2bf(va.y); v[2] = f2bf(va.z); v[3] = f2bf(va.w);
            v[4] = f2bf(vb.x); v[5] = f2bf(vb.y); v[6] = f2bf(vb.z); v[7] = f2bf(vb.w);
            *reinterpret_cast<u16x8*>(Xs + r * 512 + ((c0 * 2) ^ ((r & 7) << 4))) = v;
        }
    }
    __syncthreads();

    const int r16   = lane & 15;
    const int khalf = (lane >> 4) << 4;
    const int rbase = (lane >> 4) * 4;

    f32x4 acc[4][8];
#pragma unroll
    for (int m = 0; m < 4; ++m)
#pragma unroll
        for (int jj = 0; jj < 8; ++jj) acc[m][jj] = (f32x4){0.f, 0.f, 0.f, 0.f};

    for (int ks = 0; ks < 8; ++ks) {
        bf16x8 b[8];
#pragma unroll
        for (int jj = 0; jj < 8; ++jj)
            b[jj] = *reinterpret_cast<const bf16x8*>(
                W0p + (((size_t)(wave + 4 * jj) * 8 + ks) * 64 + lane) * 8);
        const int kb = ks * 64 + khalf;
#pragma unroll
        for (int m = 0; m < 4; ++m) {
            const int row = m * 16 + r16;
            const bf16x8 a = *reinterpret_cast<const bf16x8*>(
                Xs + row * 512 + (kb ^ ((row & 7) << 4)));
#pragma unroll
            for (int jj = 0; jj < 8; ++jj)
                acc[m][jj] = __builtin_amdgcn_mfma_f32_16x16x32_bf16(a, b[jj], acc[m][jj], 0, 0, 0);
        }
    }

#pragma unroll
    for (int jj = 0; jj < 8; ++jj) {
        const int nt = wave + 4 * jj;            // wave-uniform branch
        const bool isL = nt < 16;
        const int ncl = (isL ? nt * 16 : (nt - 16) * 16) + r16;
        const float bias = isL ? bl[ncl] : br[ncl];
        u16* base = (isL ? clb : crb) + ncl;
#pragma unroll
        for (int m = 0; m < 4; ++m)
#pragma unroll
            for (int rr = 0; rr < 4; ++rr) {
                const int node = node0 + m * 16 + rbase + rr;
                if (node < NN)
                    base[(size_t)node * CCH] = f2bf(acc[m][jj][rr] + bias);
            }
    }
}

// ---------------- K1b: fp32 -> bf16 convert (for metrics) ----------------
__global__ __launch_bounds__(256) void k_convert(
    const float* __restrict__ in, u16* __restrict__ out, int n)
{
    const int i = (blockIdx.x * 256 + threadIdx.x) * 4;
    if (i < n) {
        const float4 v = *reinterpret_cast<const float4*>(in + i);
        u16x4 o; o[0] = f2bf(v.x); o[1] = f2bf(v.y); o[2] = f2bf(v.z); o[3] = f2bf(v.w);
        *reinterpret_cast<u16x4*>(out + i) = o;
    }
}

// ---------------- K1c: pack all weights into MFMA B-fragments ------------
__device__ __forceinline__ void pack_frag(
    const float* __restrict__ W, u16* __restrict__ out, int K, int N,
    int f, int lane)
{
    const int KS = K >> 5;
    const int nt = f / KS, ks = f - nt * KS;
    const int n = nt * 16 + (lane & 15);
    const int k0 = ks * 32 + (lane >> 4) * 8;
    u16x8 v;
#pragma unroll
    for (int j = 0; j < 8; ++j) v[j] = f2bf(W[(size_t)(k0 + j) * N + n]);
    *reinterpret_cast<u16x8*>(out + ((size_t)f * 64 + lane) * 8) = v;
}

// grid = 456: [0,128) Wl, [128,256) Wr, [256,400) W1, [400,448) W2, [448,456) att
__global__ __launch_bounds__(64) void k_pack_all(
    const float* __restrict__ Wl, const float* __restrict__ Wr,
    const float* __restrict__ W1, const float* __restrict__ W2,
    const float* __restrict__ att,
    u16* __restrict__ W0p, u16* __restrict__ W1p, u16* __restrict__ W2p,
    u16* __restrict__ attp)
{
    const int b = blockIdx.x, lane = threadIdx.x;
    if (b < 128)       pack_frag(Wl, W0p, CCH, CCH, b, lane);
    else if (b < 256)  pack_frag(Wr, W0p + (size_t)128 * 64 * 8, CCH, CCH, b - 128, lane);
    else if (b < 400)  pack_frag(W1, W1p, CCH + DMC, HDC, b - 256, lane);
    else if (b < 448)  pack_frag(W2, W2p, HDC, OUTC, b - 400, lane);
    else {
        const int ks = b - 448;
        const int nloc = lane & 15;
        const int k0 = ks * 32 + (lane >> 4) * 8;
        u16x8 v;
#pragma unroll
        for (int j = 0; j < 8; ++j) v[j] = f2bf((nloc == 0) ? att[k0 + j] : 0.f);
        *reinterpret_cast<u16x8*>(attp + ((size_t)ks * 64 + lane) * 8) = v;
    }
}

// ---------------- Sort by dst: histogram -> 3-phase scan -> scatter ------
__global__ __launch_bounds__(256) void k_hist(
    const int* __restrict__ ei, int* __restrict__ cnt)
{
    const int i = blockIdx.x * 256 + threadIdx.x;
    if (i < EE / 4) {
        const int4 d = *reinterpret_cast<const int4*>(ei + EE + i * 4);
        atomicAdd(&cnt[d.x], 1); atomicAdd(&cnt[d.y], 1);
        atomicAdd(&cnt[d.z], 1); atomicAdd(&cnt[d.w], 1);
    }
}

__global__ __launch_bounds__(256) void k_scan1(
    const int* __restrict__ cnt, int* __restrict__ bsum)
{
    const int i = blockIdx.x * 256 + threadIdx.x;
    int v = (i < NN) ? cnt[i] : 0;
#pragma unroll
    for (int o = 1; o < 64; o <<= 1) v += __shfl_xor(v, o);
    __shared__ int ws[4];
    if ((threadIdx.x & 63) == 0) ws[threadIdx.x >> 6] = v;
    __syncthreads();
    if (threadIdx.x == 0) bsum[blockIdx.x] = ws[0] + ws[1] + ws[2] + ws[3];
}

__global__ __launch_bounds__(512) void k_scan2(int* __restrict__ bsum)
{
    __shared__ int s[512];
    const int t = threadIdx.x;
    const int v = (t < GS) ? bsum[t] : 0;
    s[t] = v;
    __syncthreads();
    for (int o = 1; o < 512; o <<= 1) {
        const int u = (t >= o) ? s[t - o] : 0;
        __syncthreads();
        s[t] += u;
        __syncthreads();
    }
    if (t < GS) bsum[t] = s[t] - v;             // exclusive
}

__global__ __launch_bounds__(256) void k_scan3(
    const int* __restrict__ cnt, const int* __restrict__ bsum,
    int* __restrict__ cur)
{
    const int t = threadIdx.x;
    const int i = blockIdx.x * 256 + t;
    const int lane = t & 63, w = t >> 6;
    const int v = (i < NN) ? cnt[i] : 0;
    int x = v;
#pragma unroll
    for (int o = 1; o < 64; o <<= 1) {
        const int u = __shfl_up(x, o);
        if (lane >= o) x += u;
    }
    __shared__ int wsum[4];
    if (lane == 63) wsum[w] = x;
    __syncthreads();
    int off = bsum[blockIdx.x];
    for (int k2 = 0; k2 < w; ++k2) off += wsum[k2];
    if (i < NN) cur[i] = off + x - v;           // exclusive prefix
}

// scatter sorted (src,dst) pairs as ONE packed int2
__global__ __launch_bounds__(256) void k_scatter(
    const int* __restrict__ ei, int* __restrict__ cur, int2* __restrict__ sd)
{
    const int i = blockIdx.x * 256 + threadIdx.x;
    if (i < EE) {
        const int d = ei[EE + i];
        const int pos = atomicAdd(&cur[d], 1);
        sd[pos] = make_int2(ei[i], d);
    }
}

// ---------------- K3: fused MLP; 64 edges/block, 16 waves, 2-phase X -----
// Phase A: full ctx [64][256] in LDS (32KB), GEMM1 ks0-7 + complete alpha.
// Phase B: metrics [64][128] into same buffer, GEMM1 ks8-11.
// Each wave owns 1 m-tile (acc[3]+acc3 = 16 regs) -> VGPR ~50 <= 64 ->
// 2 blocks/CU x 16 waves = 32 waves (100%), no spill.
__global__ __launch_bounds__(1024, 8) void k_edge_mlp(
    const int2* __restrict__ sd,
    const u16* __restrict__ clb, const u16* __restrict__ crb,
    const u16* __restrict__ metb, const u16* __restrict__ attp,
    float* __restrict__ sb,
    const u16* __restrict__ W1p, const float* __restrict__ b1,
    const u16* __restrict__ W2p, const float* __restrict__ b2,
    float* __restrict__ dout)
{
    __shared__ __align__(16) char Xs[ET * 512];   // X(256c)/met/H/msg, 32KB
    __shared__ int esrc[ET], edst[ET], flg[ET];
    __shared__ float exs[ET];

    const int tid  = threadIdx.x;
    const int wave = tid >> 6;
    const int lane = tid & 63;
    const int wm = wave >> 2, wn = wave & 3;
    const int ebase = blockIdx.x * ET;            // EE % ET == 0: no tail

    if (tid < ET) {
        const int2 p = sd[ebase + tid];
        esrc[tid] = p.x;
        edst[tid] = p.y;
    }
    __syncthreads();

    // ---- phase A stage: X[:,0:256] = selu(cr+cl), swizzled, stride 512B
#pragma unroll
    for (int i = 0; i < 2; ++i) {
        const int k = tid + i * 1024;
        const int t = k >> 5, c = k & 31;
        const u16x8 r = *reinterpret_cast<const u16x8*>(crb + (size_t)edst[t] * CCH + c * 8);
        const u16x8 l = *reinterpret_cast<const u16x8*>(clb + (size_t)esrc[t] * CCH + c * 8);
        u16x8 v;
#pragma unroll
        for (int j = 0; j < 8; ++j) v[j] = f2bf(selu_f(bf2f(r[j]) + bf2f(l[j])));
        *reinterpret_cast<u16x8*>(Xs + t * 512 + ((c * 16) ^ ((t & 7) << 4))) = v;
    }
    __syncthreads();                              // X-A ready

    const int r16   = lane & 15;
    const int khalf = (lane >> 4) << 4;
    const int rb4   = (lane >> 4) * 4;

    f32x4 acc[3];
    f32x4 acc3;
#pragma unroll
    for (int j = 0; j < 3; ++j) acc[j] = (f32x4){0.f, 0.f, 0.f, 0.f};
    acc3 = (f32x4){0.f, 0.f, 0.f, 0.f};

    // ---- GEMM1 phase A: ks 0..7 (ctx cols; alpha completes here)
    for (int ks = 0; ks < 8; ++ks) {
        bf16x8 b[3];
#pragma unroll
        for (int j = 0; j < 3; ++j)
            b[j] = *reinterpret_cast<const bf16x8*>(
                W1p + (((size_t)(wn + 4 * j) * 12 + ks) * 64 + lane) * 8);
        bf16x8 b3 = {};
        if (wn == 0)
            b3 = *reinterpret_cast<const bf16x8*>(attp + ((size_t)ks * 64 + lane) * 8);
        const int row = wm * 16 + r16;
        const bf16x8 a = *reinterpret_cast<const bf16x8*>(
            Xs + row * 512 + ((ks * 64 + khalf) ^ ((row & 7) << 4)));
#pragma unroll
        for (int j = 0; j < 3; ++j)
            acc[j] = __builtin_amdgcn_mfma_f32_16x16x32_bf16(a, b[j], acc[j], 0, 0, 0);
        if (wn == 0)
            acc3 = __builtin_amdgcn_mfma_f32_16x16x32_bf16(a, b3, acc3, 0, 0, 0);
    }
    __syncthreads();                              // X-A consumed

    // ---- phase B stage: metrics -> groups 0..15 of each row (+flg ballot)
    {
        const int t = tid >> 4, g = tid & 15;
        const u16x8 m = *reinterpret_cast<const u16x8*>(metb + (size_t)esrc[t] * DMC + g * 8);
        unsigned ob = 0;
#pragma unroll
        for (int j = 0; j < 8; ++j) ob |= (unsigned)m[j];
        const bool nz = (ob & 0x7fffu) != 0u;
        const unsigned long long bal = __ballot(nz);
        if ((lane & 15) == 0)
            flg[t] = (int)((bal >> ((lane >> 4) * 16)) & 0xFFFFull) != 0;
        *reinterpret_cast<u16x8*>(Xs + t * 512 + ((g * 16) ^ ((t & 7) << 4))) = m;
    }
    __syncthreads();                              // X-B + flg ready

    // alpha extraction (acc3 final after phase A): col 0 -> r16==0 lanes
    if (wn == 0 && r16 == 0) {
        const int hi = lane >> 4;
#pragma unroll
        for (int r = 0; r < 4; ++r) {
            const int e = wm * 16 + hi * 4 + r;
            const float al = acc3[r];
            exs[e] = (flg[e] && al != 0.f) ? __expf(al) : 0.f;
        }
    }

    // ---- GEMM1 phase B: ks 8..11 (metrics K-range)
    for (int ks = 8; ks < 12; ++ks) {
        bf16x8 b[3];
#pragma unroll
        for (int j = 0; j < 3; ++j)
            b[j] = *reinterpret_cast<const bf16x8*>(
                W1p + (((size_t)(wn + 4 * j) * 12 + ks) * 64 + lane) * 8);
        const int row = wm * 16 + r16;
        const bf16x8 a = *reinterpret_cast<const bf16x8*>(
            Xs + row * 512 + (((ks - 8) * 64 + khalf) ^ ((row & 7) << 4)));
#pragma unroll
        for (int j = 0; j < 3; ++j)
            acc[j] = __builtin_amdgcn_mfma_f32_16x16x32_bf16(a, b[j], acc[j], 0, 0, 0);
    }
    __syncthreads();                              // X-B consumed; exs visible

    // ---- write H (bf16, swizzled, stride 512B)
#pragma unroll
    for (int j = 0; j < 3; ++j) {
        const int n = (wn + 4 * j) * 16 + r16;
        const float bb = b1[n];
#pragma unroll
        for (int r = 0; r < 4; ++r) {
            const int row = wm * 16 + rb4 + r;
            *reinterpret_cast<u16*>(Xs + row * 512 + ((n * 2) ^ ((row & 7) << 4))) =
                f2bf(selu_f(acc[j][r] + bb));
        }
    }
    __syncthreads();

    // ---- GEMM2: F = selu(H @ W2 + b2); wave owns 1m x 2n
    f32x4 acc2[2];
#pragma unroll
    for (int j = 0; j < 2; ++j) acc2[j] = (f32x4){0.f, 0.f, 0.f, 0.f};

    for (int ks = 0; ks < 6; ++ks) {
        bf16x8 b[2];
#pragma unroll
        for (int j = 0; j < 2; ++j)
            b[j] = *reinterpret_cast<const bf16x8*>(
                W2p + (((size_t)(wn + 4 * j) * 6 + ks) * 64 + lane) * 8);
        const int row = wm * 16 + r16;
        const bf16x8 a = *reinterpret_cast<const bf16x8*>(
            Xs + row * 512 + ((ks * 64 + khalf) ^ ((row & 7) << 4)));
#pragma unroll
        for (int j = 0; j < 2; ++j)
            acc2[j] = __builtin_amdgcn_mfma_f32_16x16x32_bf16(a, b[j], acc2[j], 0, 0, 0);
    }
    __syncthreads();                              // H reads done; reuse Xs

    // ---- epilogue: bf16 msg tile, dst-segment reduce (sorted rows)
    u16* Ms = (u16*)Xs;                           // [ET][MSB] bf16, 16.9KB
#pragma unroll
    for (int j = 0; j < 2; ++j) {
        const int n = (wn + 4 * j) * 16 + r16;
        const float bb = b2[n];
#pragma unroll
        for (int r = 0; r < 4; ++r) {
            const int e = wm * 16 + rb4 + r;
            Ms[e * MSB + n] = f2bf(selu_f(acc2[j][r] + bb) * exs[e]);
        }
    }
    __syncthreads();

    {
        const int col = tid & 127;
        const int h = tid >> 7;                   // 0..7: rows [h*8, h*8+8)
        const int r0 = h * 8;
        int cur_d = edst[r0];
        float s = bf2f(Ms[r0 * MSB + col]);
        for (int r = r0 + 1; r < r0 + 8; ++r) {
            const int d = edst[r];
            const float v = bf2f(Ms[r * MSB + col]);
            if (d != cur_d) {
                if (s != 0.f) atomicAdd(&dout[(size_t)cur_d * OUTC + col], s);
                cur_d = d; s = v;
            } else {
                s += v;
            }
        }
        if (s != 0.f) atomicAdd(&dout[(size_t)cur_d * OUTC + col], s);
    }
    if (tid < 8) {                                // ex segment-reduce -> sb
        const int r0 = tid * 8;
        int cur_d = edst[r0];
        float s = exs[r0];
        for (int r = r0 + 1; r < r0 + 8; ++r) {
            const int d = edst[r];
            const float v = exs[r];
            if (d != cur_d) {
                if (s != 0.f) atomicAdd(&sb[cur_d], s);
                cur_d = d; s = v;
            } else {
                s += v;
            }
        }
        if (s != 0.f) atomicAdd(&sb[cur_d], s);
    }
}

// ---------------- K4: finalize: divide by sum, overwrite-or-sigmoid ------
__global__ __launch_bounds__(256) void k_finalize(
    float* __restrict__ dout, const float* __restrict__ met,
    const float* __restrict__ bias, const float* __restrict__ sb)
{
    const int n = blockIdx.x * 4 + (threadIdx.x >> 6);
    const int lane = threadIdx.x & 63;
    const float a0 = dout[(size_t)n * OUTC + lane];
    const float a1 = dout[(size_t)n * OUTC + 64 + lane];
    const bool ovr = __all((a0 == 0.f) && (a1 == 0.f));
    float r0, r1;
    if (ovr) {
        r0 = met[(size_t)n * DMC + lane];
        r1 = met[(size_t)n * DMC + 64 + lane];
    } else {
        const float inv = 1.0f / (sb[n] + 1e-16f);
        r0 = 1.f / (1.f + __expf(-(a0 * inv + bias[lane])));
        r1 = 1.f / (1.f + __expf(-(a1 * inv + bias[64 + lane])));
    }
    dout[(size_t)n * OUTC + lane] = r0;
    dout[(size_t)n * OUTC + 64 + lane] = r1;
}

extern "C" void kernel_launch(void* const* d_in, const int* in_sizes, int n_in,
                              void* d_out, int out_size, void* d_ws, size_t ws_size,
                              hipStream_t stream)
{
    const int*   ei   = (const int*)d_in[0];
    const float* ss   = (const float*)d_in[1];
    const float* se   = (const float*)d_in[2];
    const float* ctx  = (const float*)d_in[3];
    const float* met  = (const float*)d_in[4];
    const float* Wl   = (const float*)d_in[5];
    const float* bl   = (const float*)d_in[6];
    const float* Wr   = (const float*)d_in[7];
    const float* br   = (const float*)d_in[8];
    const float* att  = (const float*)d_in[9];
    const float* W1   = (const float*)d_in[10];
    const float* b1   = (const float*)d_in[11];
    const float* W2   = (const float*)d_in[12];
    const float* b2   = (const float*)d_in[13];
    const float* bias = (const float*)d_in[14];

    u16* clb  = (u16*)d_ws;
    u16* crb  = clb  + (size_t)NN * CCH;
    u16* metb = crb  + (size_t)NN * CCH;
    u16* W1p  = metb + (size_t)NN * DMC;
    u16* W2p  = W1p  + (size_t)(CCH + DMC) * HDC;
    u16* W0p  = W2p  + (size_t)HDC * OUTC;
    float* sb = (float*)(W0p + (size_t)CCH * 512);
    int* cnt  = (int*)(sb + NN);      // adjacent to sb: one fused memset
    int* cur  = cnt + NN;
    int2* sd  = (int2*)(cur + NN);
    int* bsum = (int*)(sd + EE);
    u16* attp = (u16*)(bsum + 512);

    float* dout = (float*)d_out;

    hipMemsetAsync(dout, 0, (size_t)NN * OUTC * sizeof(float), stream);
    hipMemsetAsync(sb, 0, (size_t)NN * 2 * sizeof(float), stream);  // sb + cnt

    // dst-sort: histogram -> coalesced 3-phase scan -> scatter packed pairs
    k_hist<<<(EE / 4 + 255) / 256, 256, 0, stream>>>(ei, cnt);
    k_scan1<<<GS, 256, 0, stream>>>(cnt, bsum);
    k_scan2<<<1, 512, 0, stream>>>(bsum);
    k_scan3<<<GS, 256, 0, stream>>>(cnt, bsum, cur);
    k_scatter<<<(EE + 255) / 256, 256, 0, stream>>>(ei, cur, sd);

    // pack all weights in one launch; convert metrics
    k_pack_all<<<456, 64, 0, stream>>>(Wl, Wr, W1, W2, att, W0p, W1p, W2p, attp);
    k_convert<<<(NN * DMC / 4 + 255) / 256, 256, 0, stream>>>(met, metb, NN * DMC);

    k_node_gemm<<<(NN + 63) / 64, 256, 0, stream>>>(ss, se, ctx, W0p, bl, br, clb, crb);
    k_edge_mlp<<<EE / ET, 1024, 0, stream>>>(sd, clb, crb, metb, attp, sb,
                                             W1p, b1, W2p, b2, dout);
    k_finalize<<<NN / 4, 256, 0, stream>>>(dout, met, bias, sb);
}

// Round 13
// 674.715 us; speedup vs baseline: 1.2929x; 1.2929x over previous
//
#include <hip/hip_runtime.h>
#include <hip/hip_bf16.h>
#include <math.h>

#define NN   100000
#define EE   1000000
#define CCH  256      // context channels
#define DMC  128      // stage_metrics channels
#define HDC  192      // hidden of final transform
#define OUTC 128      // out channels
#define ET   64       // edges per k_edge_mlp block (4 m-tiles); EE%ET==0
#define MS   132      // LDS msg-tile row stride (128 cols + ex col 128)
#define GS   391      // scan grid: ceil(NN/256)
#define PPK  114      // prep: pack blocks (114*4 = 456 frags)
#define PCV  12500    // prep: convert blocks (NN*DMC/4/256)
#define PHS  977      // prep: hist blocks (ceil(EE/4/256))

typedef unsigned short u16;
using bf16x8 = __attribute__((ext_vector_type(8))) short;
using f32x4  = __attribute__((ext_vector_type(4))) float;
using u16x4  = __attribute__((ext_vector_type(4))) unsigned short;
using u16x8  = __attribute__((ext_vector_type(8))) unsigned short;

__device__ __forceinline__ float selu_f(float x) {
    const float sc = 1.0507009873554804934193349852946f;
    const float c1 = 1.7580993408473765792727863477367f;  // sc*alpha
    const float e = __expf(x);
    return x > 0.0f ? sc * x : __builtin_fmaf(c1, e, -c1);
}
__device__ __forceinline__ u16 f2bf(float f) {
    union { __hip_bfloat16 h; u16 u; } c;
    c.h = __float2bfloat16(f);
    return c.u;
}
__device__ __forceinline__ float bf2f(u16 h) {
    return __uint_as_float(((unsigned int)h) << 16);
}

// ---------------- K1: node transform as bf16 MFMA GEMM -------------------
__global__ __launch_bounds__(256, 2) void k_node_gemm(
    const float* __restrict__ ss, const float* __restrict__ se,
    const float* __restrict__ ctx, const u16* __restrict__ W0p,
    const float* __restrict__ bl, const float* __restrict__ br,
    u16* __restrict__ clb, u16* __restrict__ crb)
{
    __shared__ __align__(16) char Xs[64 * 512];  // [64][256] bf16 swizzled
    const int tid = threadIdx.x;
    const int wave = tid >> 6, lane = tid & 63;
    const int node0 = blockIdx.x * 64;

    {
        const int r = lane;
        const int nd = min(node0 + r, NN - 1);
#pragma unroll
        for (int i = 0; i < 8; ++i) {
            const int c0 = wave * 64 + i * 8;
            float4 va, vb;
            {
                const int c = c0;
                if (c < 16)       va = *reinterpret_cast<const float4*>(ss + nd * 16 + c);
                else if (c < 240) va = *reinterpret_cast<const float4*>(ctx + (size_t)nd * 224 + (c - 16));
                else              va = *reinterpret_cast<const float4*>(se + nd * 16 + (c - 240));
            }
            {
                const int c = c0 + 4;
                if (c < 16)       vb = *reinterpret_cast<const float4*>(ss + nd * 16 + c);
                else if (c < 240) vb = *reinterpret_cast<const float4*>(ctx + (size_t)nd * 224 + (c - 16));
                else              vb = *reinterpret_cast<const float4*>(se + nd * 16 + (c - 240));
            }
            u16x8 v;
            v[0] = f2bf(va.x); v[1] = f2bf(va.y); v[2] = f2bf(va.z); v[3] = f2bf(va.w);
            v[4] = f2bf(vb.x); v[5] = f2bf(vb.y); v[6] = f2bf(vb.z); v[7] = f2bf(vb.w);
            *reinterpret_cast<u16x8*>(Xs + r * 512 + ((c0 * 2) ^ ((r & 7) << 4))) = v;
        }
    }
    __syncthreads();

    const int r16   = lane & 15;
    const int khalf = (lane >> 4) << 4;
    const int rbase = (lane >> 4) * 4;

    f32x4 acc[4][8];
#pragma unroll
    for (int m = 0; m < 4; ++m)
#pragma unroll
        for (int jj = 0; jj < 8; ++jj) acc[m][jj] = (f32x4){0.f, 0.f, 0.f, 0.f};

    for (int ks = 0; ks < 8; ++ks) {
        bf16x8 b[8];
#pragma unroll
        for (int jj = 0; jj < 8; ++jj)
            b[jj] = *reinterpret_cast<const bf16x8*>(
                W0p + (((size_t)(wave + 4 * jj) * 8 + ks) * 64 + lane) * 8);
        const int kb = ks * 64 + khalf;
#pragma unroll
        for (int m = 0; m < 4; ++m) {
            const int row = m * 16 + r16;
            const bf16x8 a = *reinterpret_cast<const bf16x8*>(
                Xs + row * 512 + (kb ^ ((row & 7) << 4)));
#pragma unroll
            for (int jj = 0; jj < 8; ++jj)
                acc[m][jj] = __builtin_amdgcn_mfma_f32_16x16x32_bf16(a, b[jj], acc[m][jj], 0, 0, 0);
        }
    }

#pragma unroll
    for (int jj = 0; jj < 8; ++jj) {
        const int nt = wave + 4 * jj;            // wave-uniform branch
        const bool isL = nt < 16;
        const int ncl = (isL ? nt * 16 : (nt - 16) * 16) + r16;
        const float bias = isL ? bl[ncl] : br[ncl];
        u16* base = (isL ? clb : crb) + ncl;
#pragma unroll
        for (int m = 0; m < 4; ++m)
#pragma unroll
            for (int rr = 0; rr < 4; ++rr) {
                const int node = node0 + m * 16 + rbase + rr;
                if (node < NN)
                    base[(size_t)node * CCH] = f2bf(acc[m][jj][rr] + bias);
            }
    }
}

// ---------------- helpers for k_prep -------------------------------------
__device__ __forceinline__ void pack_frag(
    const float* __restrict__ W, u16* __restrict__ out, int K, int N,
    int f, int lane)
{
    const int KS = K >> 5;
    const int nt = f / KS, ks = f - nt * KS;
    const int n = nt * 16 + (lane & 15);
    const int k0 = ks * 32 + (lane >> 4) * 8;
    u16x8 v;
#pragma unroll
    for (int j = 0; j < 8; ++j) v[j] = f2bf(W[(size_t)(k0 + j) * N + n]);
    *reinterpret_cast<u16x8*>(out + ((size_t)f * 64 + lane) * 8) = v;
}

// ---------------- K_prep: fused weight-pack + metrics-convert + histogram
// blocks [0,PPK): pack 4 frags each; [PPK,PPK+PCV): convert; rest: hist.
__global__ __launch_bounds__(256) void k_prep(
    const float* __restrict__ Wl, const float* __restrict__ Wr,
    const float* __restrict__ W1, const float* __restrict__ W2,
    const float* __restrict__ att, const float* __restrict__ met,
    const int* __restrict__ ei,
    u16* __restrict__ W0p, u16* __restrict__ W1p, u16* __restrict__ W2p,
    u16* __restrict__ attp, u16* __restrict__ metb, int* __restrict__ cnt)
{
    const int b = blockIdx.x, tid = threadIdx.x;
    if (b < PPK) {
        const int f = b * 4 + (tid >> 6);
        const int lane = tid & 63;
        if (f < 128)       pack_frag(Wl, W0p, CCH, CCH, f, lane);
        else if (f < 256)  pack_frag(Wr, W0p + (size_t)128 * 64 * 8, CCH, CCH, f - 128, lane);
        else if (f < 400)  pack_frag(W1, W1p, CCH + DMC, HDC, f - 256, lane);
        else if (f < 448)  pack_frag(W2, W2p, HDC, OUTC, f - 400, lane);
        else {
            const int ks = f - 448;
            const int nloc = lane & 15;
            const int k0 = ks * 32 + (lane >> 4) * 8;
            u16x8 v;
#pragma unroll
            for (int j = 0; j < 8; ++j) v[j] = f2bf((nloc == 0) ? att[k0 + j] : 0.f);
            *reinterpret_cast<u16x8*>(attp + ((size_t)ks * 64 + lane) * 8) = v;
        }
    } else if (b < PPK + PCV) {
        const int i = ((b - PPK) * 256 + tid) * 4;
        const float4 v = *reinterpret_cast<const float4*>(met + i);
        u16x4 o; o[0] = f2bf(v.x); o[1] = f2bf(v.y); o[2] = f2bf(v.z); o[3] = f2bf(v.w);
        *reinterpret_cast<u16x4*>(metb + i) = o;
    } else {
        const int i = (b - PPK - PCV) * 256 + tid;
        if (i < EE / 4) {
            const int4 d = *reinterpret_cast<const int4*>(ei + EE + i * 4);
            atomicAdd(&cnt[d.x], 1); atomicAdd(&cnt[d.y], 1);
            atomicAdd(&cnt[d.z], 1); atomicAdd(&cnt[d.w], 1);
        }
    }
}

// ---------------- Sort by dst: 3-phase scan -> scatter -------------------
__global__ __launch_bounds__(256) void k_scan1(
    const int* __restrict__ cnt, int* __restrict__ bsum)
{
    const int i = blockIdx.x * 256 + threadIdx.x;
    int v = (i < NN) ? cnt[i] : 0;
#pragma unroll
    for (int o = 1; o < 64; o <<= 1) v += __shfl_xor(v, o);
    __shared__ int ws[4];
    if ((threadIdx.x & 63) == 0) ws[threadIdx.x >> 6] = v;
    __syncthreads();
    if (threadIdx.x == 0) bsum[blockIdx.x] = ws[0] + ws[1] + ws[2] + ws[3];
}

__global__ __launch_bounds__(512) void k_scan2(int* __restrict__ bsum)
{
    __shared__ int s[512];
    const int t = threadIdx.x;
    const int v = (t < GS) ? bsum[t] : 0;
    s[t] = v;
    __syncthreads();
    for (int o = 1; o < 512; o <<= 1) {
        const int u = (t >= o) ? s[t - o] : 0;
        __syncthreads();
        s[t] += u;
        __syncthreads();
    }
    if (t < GS) bsum[t] = s[t] - v;             // exclusive
}

__global__ __launch_bounds__(256) void k_scan3(
    const int* __restrict__ cnt, const int* __restrict__ bsum,
    int* __restrict__ cur)
{
    const int t = threadIdx.x;
    const int i = blockIdx.x * 256 + t;
    const int lane = t & 63, w = t >> 6;
    const int v = (i < NN) ? cnt[i] : 0;
    int x = v;
#pragma unroll
    for (int o = 1; o < 64; o <<= 1) {
        const int u = __shfl_up(x, o);
        if (lane >= o) x += u;
    }
    __shared__ int wsum[4];
    if (lane == 63) wsum[w] = x;
    __syncthreads();
    int off = bsum[blockIdx.x];
    for (int k2 = 0; k2 < w; ++k2) off += wsum[k2];
    if (i < NN) cur[i] = off + x - v;           // exclusive prefix
}

// scatter sorted (src,dst) pairs as ONE packed int2
__global__ __launch_bounds__(256) void k_scatter(
    const int* __restrict__ ei, int* __restrict__ cur, int2* __restrict__ sd)
{
    const int i = blockIdx.x * 256 + threadIdx.x;
    if (i < EE) {
        const int d = ei[EE + i];
        const int pos = atomicAdd(&cur[d], 1);
        sd[pos] = make_int2(ei[i], d);
    }
}

// ---------------- K3: fused MLP; 64 edges/block, 8 waves (round-10 best) -
// wave w = (wm,wn) = (w>>2, w&3). GEMM1: wave owns m{2wm,2wm+1} x n{wn,wn+4,wn+8}.
// GEMM2: m{2wm,2wm+1} x n{wn,wn+4}. Alpha (N-tile 12): wn==0 waves, ks<8.
__global__ __launch_bounds__(512, 6) void k_edge_mlp(
    const int2* __restrict__ sd,
    const u16* __restrict__ clb, const u16* __restrict__ crb,
    const u16* __restrict__ metb, const u16* __restrict__ attp,
    float* __restrict__ sb,
    const u16* __restrict__ W1p, const float* __restrict__ b1,
    const u16* __restrict__ W2p, const float* __restrict__ b2,
    float* __restrict__ dout)
{
    __shared__ __align__(16) char Xs[ET * 768];   // X [64][384]bf16 / H / msg-tile
    __shared__ int esrc[ET], edst[ET], flg[ET];
    __shared__ float exs[ET];

    const int tid  = threadIdx.x;
    const int wave = tid >> 6;
    const int lane = tid & 63;
    const int wm = wave >> 2, wn = wave & 3;
    const int ebase = blockIdx.x * ET;            // EE % ET == 0: no tail

    if (tid < ET) {
        const int2 p = sd[ebase + tid];
        esrc[tid] = p.x;
        edst[tid] = p.y;
    }
    __syncthreads();

    // ---- X-build: batch gathers, then convert+store (swizzled bf16)
    u16x8 rv[4], lv[4], mv[2];
#pragma unroll
    for (int i = 0; i < 4; ++i) {
        const int k = tid + i * 512;
        const int t = k >> 5, c = k & 31;
        rv[i] = *reinterpret_cast<const u16x8*>(crb + (size_t)edst[t] * CCH + c * 8);
        lv[i] = *reinterpret_cast<const u16x8*>(clb + (size_t)esrc[t] * CCH + c * 8);
    }
#pragma unroll
    for (int i = 0; i < 2; ++i) {
        const int k = tid + i * 512;
        mv[i] = *reinterpret_cast<const u16x8*>(metb + (size_t)esrc[k >> 4] * DMC + (k & 15) * 8);
    }
#pragma unroll
    for (int i = 0; i < 4; ++i) {
        const int k = tid + i * 512;
        const int t = k >> 5, c = k & 31;
        u16x8 v;
#pragma unroll
        for (int j = 0; j < 8; ++j) v[j] = f2bf(selu_f(bf2f(rv[i][j]) + bf2f(lv[i][j])));
        *reinterpret_cast<u16x8*>(Xs + t * 768 + ((c * 16) ^ ((t & 7) << 4))) = v;
    }
#pragma unroll
    for (int i = 0; i < 2; ++i) {
        const int k = tid + i * 512;
        const int t = k >> 4, g = k & 15;
        unsigned ob = 0;
#pragma unroll
        for (int j = 0; j < 8; ++j) ob |= (unsigned)mv[i][j];
        const bool nz = (ob & 0x7fffu) != 0u;
        const unsigned long long bal = __ballot(nz);
        if ((lane & 15) == 0)
            flg[t] = (int)((bal >> ((lane >> 4) * 16)) & 0xFFFFull) != 0;
        *reinterpret_cast<u16x8*>(Xs + t * 768 + (((32 + g) * 16) ^ ((t & 7) << 4))) = mv[i];
    }
    __syncthreads();

    const int r16   = lane & 15;
    const int khalf = (lane >> 4) << 4;
    const int rbase = (lane >> 4) * 4;

    // ---- GEMM1: H = selu(X @ W1 + b1); + alpha tile on wn==0 waves
    f32x4 acc[2][3];
    f32x4 acc3[2];
#pragma unroll
    for (int m = 0; m < 2; ++m) {
#pragma unroll
        for (int j = 0; j < 3; ++j) acc[m][j] = (f32x4){0.f, 0.f, 0.f, 0.f};
        acc3[m] = (f32x4){0.f, 0.f, 0.f, 0.f};
    }

    for (int ks = 0; ks < 12; ++ks) {
        bf16x8 b[3];
#pragma unroll
        for (int j = 0; j < 3; ++j)
            b[j] = *reinterpret_cast<const bf16x8*>(
                W1p + (((size_t)(wn + 4 * j) * 12 + ks) * 64 + lane) * 8);
        bf16x8 b3 = {};
        const bool doA = (wn == 0) && (ks < 8);
        if (doA)
            b3 = *reinterpret_cast<const bf16x8*>(attp + ((size_t)ks * 64 + lane) * 8);
        const int kb = ks * 64 + khalf;
#pragma unroll
        for (int m = 0; m < 2; ++m) {
            const int row = (wm * 2 + m) * 16 + r16;
            const bf16x8 a = *reinterpret_cast<const bf16x8*>(
                Xs + row * 768 + (kb ^ ((row & 7) << 4)));
#pragma unroll
            for (int j = 0; j < 3; ++j)
                acc[m][j] = __builtin_amdgcn_mfma_f32_16x16x32_bf16(a, b[j], acc[m][j], 0, 0, 0);
            if (doA)
                acc3[m] = __builtin_amdgcn_mfma_f32_16x16x32_bf16(a, b3, acc3[m], 0, 0, 0);
        }
    }

    // alpha extraction: col 0 of tile 12 -> lanes with (lane&15)==0
    if (wn == 0 && r16 == 0) {
        const int hi = lane >> 4;
#pragma unroll
        for (int m = 0; m < 2; ++m)
#pragma unroll
            for (int r = 0; r < 4; ++r) {
                const int e = (wm * 2 + m) * 16 + hi * 4 + r;
                const float al = acc3[m][r];
                exs[e] = (flg[e] && al != 0.f) ? __expf(al) : 0.f;
            }
    }
    __syncthreads();   // X/exs settle before overwrite with H

    // ---- write H (bf16, swizzled, row stride 384B)
#pragma unroll
    for (int j = 0; j < 3; ++j) {
        const int n = (wn + 4 * j) * 16 + r16;
        const float bb = b1[n];
#pragma unroll
        for (int m = 0; m < 2; ++m)
#pragma unroll
            for (int r = 0; r < 4; ++r) {
                const int row = (wm * 2 + m) * 16 + rbase + r;
                *reinterpret_cast<u16*>(Xs + row * 384 + ((n * 2) ^ ((row & 7) << 4))) =
                    f2bf(selu_f(acc[m][j][r] + bb));
            }
    }
    __syncthreads();

    // ---- GEMM2: F = selu(H @ W2 + b2)
    f32x4 acc2[2][2];
#pragma unroll
    for (int m = 0; m < 2; ++m)
#pragma unroll
        for (int j = 0; j < 2; ++j) acc2[m][j] = (f32x4){0.f, 0.f, 0.f, 0.f};

    for (int ks = 0; ks < 6; ++ks) {
        bf16x8 b[2];
#pragma unroll
        for (int j = 0; j < 2; ++j)
            b[j] = *reinterpret_cast<const bf16x8*>(
                W2p + (((size_t)(wn + 4 * j) * 6 + ks) * 64 + lane) * 8);
        const int kb = ks * 64 + khalf;
#pragma unroll
        for (int m = 0; m < 2; ++m) {
            const int row = (wm * 2 + m) * 16 + r16;
            const bf16x8 a = *reinterpret_cast<const bf16x8*>(
                Xs + row * 384 + (kb ^ ((row & 7) << 4)));
#pragma unroll
            for (int j = 0; j < 2; ++j)
                acc2[m][j] = __builtin_amdgcn_mfma_f32_16x16x32_bf16(a, b[j], acc2[m][j], 0, 0, 0);
        }
    }
    __syncthreads();   // all H reads done before Xs is reused as msg tile

    // ---- epilogue: msg tile (+ex col 128) to LDS, dst-segment reduce
    float* Ms = (float*)Xs;                       // [ET][MS] f32, 33.8KB
#pragma unroll
    for (int j = 0; j < 2; ++j) {
        const int n = (wn + 4 * j) * 16 + r16;
        const float bb = b2[n];
#pragma unroll
        for (int m = 0; m < 2; ++m)
#pragma unroll
            for (int r = 0; r < 4; ++r) {
                const int e = (wm * 2 + m) * 16 + rbase + r;
                Ms[e * MS + n] = selu_f(acc2[m][j][r] + bb) * exs[e];
            }
    }
    if (tid < ET) Ms[tid * MS + 128] = exs[tid];
    __syncthreads();

    {
        const int col = tid & 127;
        const int h = tid >> 7;                   // 0..3: rows [h*16, h*16+16)
        const int r0 = h * 16;
        int cur_d = edst[r0];
        float s = Ms[r0 * MS + col];
        for (int r = r0 + 1; r < r0 + 16; ++r) {
            const int d = edst[r];
            const float v = Ms[r * MS + col];
            if (d != cur_d) {
                if (s != 0.f) atomicAdd(&dout[(size_t)cur_d * OUTC + col], s);
                cur_d = d; s = v;
            } else {
                s += v;
            }
        }
        if (s != 0.f) atomicAdd(&dout[(size_t)cur_d * OUTC + col], s);
    }
    if (tid < 4) {                                // ex segment-reduce -> sb
        const int r0 = tid * 16;
        int cur_d = edst[r0];
        float s = Ms[r0 * MS + 128];
        for (int r = r0 + 1; r < r0 + 16; ++r) {
            const int d = edst[r];
            const float v = Ms[r * MS + 128];
            if (d != cur_d) {
                if (s != 0.f) atomicAdd(&sb[cur_d], s);
                cur_d = d; s = v;
            } else {
                s += v;
            }
        }
        if (s != 0.f) atomicAdd(&sb[cur_d], s);
    }
}

// ---------------- K4: finalize: divide by sum, overwrite-or-sigmoid ------
__global__ __launch_bounds__(256) void k_finalize(
    float* __restrict__ dout, const float* __restrict__ met,
    const float* __restrict__ bias, const float* __restrict__ sb)
{
    const int n = blockIdx.x * 4 + (threadIdx.x >> 6);
    const int lane = threadIdx.x & 63;
    const float a0 = dout[(size_t)n * OUTC + lane];
    const float a1 = dout[(size_t)n * OUTC + 64 + lane];
    const bool ovr = __all((a0 == 0.f) && (a1 == 0.f));
    float r0, r1;
    if (ovr) {
        r0 = met[(size_t)n * DMC + lane];
        r1 = met[(size_t)n * DMC + 64 + lane];
    } else {
        const float inv = 1.0f / (sb[n] + 1e-16f);
        r0 = 1.f / (1.f + __expf(-(a0 * inv + bias[lane])));
        r1 = 1.f / (1.f + __expf(-(a1 * inv + bias[64 + lane])));
    }
    dout[(size_t)n * OUTC + lane] = r0;
    dout[(size_t)n * OUTC + 64 + lane] = r1;
}

extern "C" void kernel_launch(void* const* d_in, const int* in_sizes, int n_in,
                              void* d_out, int out_size, void* d_ws, size_t ws_size,
                              hipStream_t stream)
{
    const int*   ei   = (const int*)d_in[0];
    const float* ss   = (const float*)d_in[1];
    const float* se   = (const float*)d_in[2];
    const float* ctx  = (const float*)d_in[3];
    const float* met  = (const float*)d_in[4];
    const float* Wl   = (const float*)d_in[5];
    const float* bl   = (const float*)d_in[6];
    const float* Wr   = (const float*)d_in[7];
    const float* br   = (const float*)d_in[8];
    const float* att  = (const float*)d_in[9];
    const float* W1   = (const float*)d_in[10];
    const float* b1   = (const float*)d_in[11];
    const float* W2   = (const float*)d_in[12];
    const float* b2   = (const float*)d_in[13];
    const float* bias = (const float*)d_in[14];

    u16* clb  = (u16*)d_ws;
    u16* crb  = clb  + (size_t)NN * CCH;
    u16* metb = crb  + (size_t)NN * CCH;
    u16* W1p  = metb + (size_t)NN * DMC;
    u16* W2p  = W1p  + (size_t)(CCH + DMC) * HDC;
    u16* W0p  = W2p  + (size_t)HDC * OUTC;
    float* sb = (float*)(W0p + (size_t)CCH * 512);
    int* cnt  = (int*)(sb + NN);      // adjacent to sb: one fused memset
    int* cur  = cnt + NN;
    int2* sd  = (int2*)(cur + NN);
    int* bsum = (int*)(sd + EE);
    u16* attp = (u16*)(bsum + 512);

    float* dout = (float*)d_out;

    hipMemsetAsync(dout, 0, (size_t)NN * OUTC * sizeof(float), stream);
    hipMemsetAsync(sb, 0, (size_t)NN * 2 * sizeof(float), stream);  // sb + cnt

    // fused pack + convert + histogram
    k_prep<<<PPK + PCV + PHS, 256, 0, stream>>>(Wl, Wr, W1, W2, att, met, ei,
                                                W0p, W1p, W2p, attp, metb, cnt);

    // dst-sort: coalesced 3-phase scan -> scatter packed pairs
    k_scan1<<<GS, 256, 0, stream>>>(cnt, bsum);
    k_scan2<<<1, 512, 0, stream>>>(bsum);
    k_scan3<<<GS, 256, 0, stream>>>(cnt, bsum, cur);
    k_scatter<<<(EE + 255) / 256, 256, 0, stream>>>(ei, cur, sd);

    k_node_gemm<<<(NN + 63) / 64, 256, 0, stream>>>(ss, se, ctx, W0p, bl, br, clb, crb);
    k_edge_mlp<<<EE / ET, 512, 0, stream>>>(sd, clb, crb, metb, attp, sb,
                                            W1p, b1, W2p, b2, dout);
    k_finalize<<<NN / 4, 256, 0, stream>>>(dout, met, bias, sb);
}